// Round 11
// baseline (1605.725 us; speedup 1.0000x reference)
//
#include <hip/hip_runtime.h>

typedef unsigned short u16;
typedef unsigned int   u32;
typedef __attribute__((ext_vector_type(8))) short short8;
typedef __attribute__((ext_vector_type(4))) float f32x4;

struct __align__(8) u16x4 { u16 x, y, z, w; };

#define NL 7
#define M_DIM 131072              // B*S = 256*512

__device__ __forceinline__ float b2f(u16 u) {
  union { float f; u32 i; } c; c.i = ((u32)u) << 16; return c.f;
}
__device__ __forceinline__ u16 f2b(float f) {
  union { float f; u32 i; } c; c.f = f;
  u32 r = c.i + 0x7FFFu + ((c.i >> 16) & 1u);
  return (u16)(r >> 16);
}
__device__ __forceinline__ float wave_sum(float v) {
  #pragma unroll
  for (int off = 1; off < 64; off <<= 1) v += __shfl_xor(v, off);
  return v;
}
__device__ __forceinline__ void gload16(const void* g, void* l) {
  __builtin_amdgcn_global_load_lds((const __attribute__((address_space(1))) void*)g,
                                   (__attribute__((address_space(3))) void*)l, 16, 0, 0);
}

// ---------------- weight conversion (fp32 -> bf16, transposed to [N][K]) ----------------

__global__ __launch_bounds__(256) void conv_w1_k(const float* __restrict__ w1, u16* __restrict__ wT) {
  int idx = blockIdx.x * 256 + threadIdx.x;            // NL*256*256 ; [i][n][k]
  int i = idx >> 16, rem = idx & 65535;
  int n = rem >> 8, k = rem & 255;
  wT[idx] = f2b(w1[(i << 16) + (k << 8) + n]);
}

__global__ __launch_bounds__(256) void conv_wd_k(const float* __restrict__ wd, u16* __restrict__ wT) {
  int idx = blockIdx.x * 256 + threadIdx.x;            // NL*256*512 ; [i][n][k2], k2=tap*256+k
  int i = idx / 131072, rem = idx & 131071;
  int n = rem >> 9, k2 = rem & 511;
  int tap = k2 >> 8, k = k2 & 255;
  wT[idx] = f2b(wd[(((i * 2 + tap) << 8) + k) * 256 + n]);
}

__global__ __launch_bounds__(256) void conv_weg_k(const float* __restrict__ we, const float* __restrict__ wg,
                                                  u16* __restrict__ wT) {
  int idx = blockIdx.x * 256 + threadIdx.x;            // NL*2*256*256 ; [i][src][n][k]
  int i = idx / 131072, rem = idx & 131071;
  int src = rem >> 16, n = (rem >> 8) & 255, k = rem & 255;
  const float* W = src ? wg : we;
  wT[idx] = f2b(W[((i << 8) + k) * 256 + n]);
}

__global__ __launch_bounds__(256) void conv_wo_k(const float* __restrict__ outW, u16* __restrict__ wTo) {
  int idx = blockIdx.x * 256 + threadIdx.x;            // 32*256 ; [v][k]
  int v = idx >> 8, k = idx & 255;
  wTo[idx] = f2b(outW[k * 32 + v]);
}

// ---------------- zlat = z @ latent_W + latent_b  [256,256] fp32 ----------------

__global__ __launch_bounds__(256) void zlat_k(const float* __restrict__ z, const float* __restrict__ W,
                                              const float* __restrict__ bias, float* __restrict__ zlat) {
  int b = blockIdx.x, c = threadIdx.x;
  float acc = bias[c];
  for (int l = 0; l < 256; ++l) acc += z[b * 256 + l] * W[l * 256 + c];
  zlat[b * 256 + c] = acc;
}

// ---------------- LN(+lrelu) helper for embed: 1 wave per 256-wide row ----------------

__device__ __forceinline__ void ln_lrelu4(float v0, float v1, float v2, float v3,
                                          const float* __restrict__ g, const float* __restrict__ b,
                                          int c, u16x4* out) {
  float s = wave_sum(v0 + v1 + v2 + v3);
  float q = wave_sum(v0 * v0 + v1 * v1 + v2 * v2 + v3 * v3);
  float mu = s * 0.00390625f;
  float var = q * 0.00390625f - mu * mu;
  float rs = rsqrtf(var + 1e-5f);
  float4 gv = *(const float4*)&g[c];
  float4 bv = *(const float4*)&b[c];
  float y0 = (v0 - mu) * rs * gv.x + bv.x; y0 = y0 >= 0.f ? y0 : 0.01f * y0;
  float y1 = (v1 - mu) * rs * gv.y + bv.y; y1 = y1 >= 0.f ? y1 : 0.01f * y1;
  float y2 = (v2 - mu) * rs * gv.z + bv.z; y2 = y2 >= 0.f ? y2 : 0.01f * y2;
  float y3 = (v3 - mu) * rs * gv.w + bv.w; y3 = y3 >= 0.f ? y3 : 0.01f * y3;
  out->x = f2b(y0); out->y = f2b(y1); out->z = f2b(y2); out->w = f2b(y3);
}

// ---------------- embed + zlat broadcast -> h (bf16); LN1[0]+lrelu -> t ----------------

__global__ __launch_bounds__(256) void embed_ln_k(const int* __restrict__ x, const float* __restrict__ emb,
                                                  const float* __restrict__ zlat,
                                                  const float* __restrict__ g, const float* __restrict__ b,
                                                  u16* __restrict__ h, u16* __restrict__ tOut) {
  int wave = threadIdx.x >> 6, lane = threadIdx.x & 63;
  int r = blockIdx.x * 4 + wave;
  int c = lane * 4;
  int tok = x[r];
  int bi = r >> 9;
  float4 ev = *(const float4*)&emb[tok * 256 + c];
  float4 zv = *(const float4*)&zlat[bi * 256 + c];
  float v0 = ev.x + zv.x, v1 = ev.y + zv.y, v2 = ev.z + zv.z, v3 = ev.w + zv.w;
  u16x4 hb; hb.x = f2b(v0); hb.y = f2b(v1); hb.z = f2b(v2); hb.w = f2b(v3);
  *(u16x4*)&h[(long)r * 256 + c] = hb;
  u16x4 ov;
  ln_lrelu4(v0, v1, v2, v3, g, b, c, &ov);
  *(u16x4*)&tOut[(long)r * 256 + c] = ov;
}

// ---------------- fused GEMM + bias + LN + lrelu, BK=64 ----------------
// Tile M=128 x N=256. 512 threads, 8 waves (mw 2 x nw 4), wave-tile 64x64.
// Each kt stages TWO 32-k sub-tiles (zero-conflict swizzle per sub-tile), runs 2 MFMA
// rounds between one barrier pair -> half the vmcnt-drain rounds of BK=32.

__global__ __launch_bounds__(512, 4) void gemm_ln_k(
    const u16* __restrict__ A, const u16* __restrict__ WT, int Ktot, int dil,
    const float* __restrict__ bias, const float* __restrict__ g, const float* __restrict__ b,
    u16* __restrict__ Out)
{
  __shared__ u16 lA[128 * 64];        // sub0 [0,4096), sub1 [4096,8192)  (u16 idx)
  __shared__ u16 lB[256 * 64];        // sub0 [0,8192), sub1 [8192,16384)
  __shared__ float pS[128][4], pQ[128][4];
  __shared__ float muA[128], rsA[128];
  const int tid = threadIdx.x;
  const int lane = tid & 63;
  const int wv = tid >> 6;            // 0..7
  const int mw = wv >> 2;             // 0..1
  const int nw = wv & 3;              // 0..3
  const int m0 = blockIdx.x * 128;
  const int rA = tid >> 2;            // 0..127
  const int cSw = ((((tid & 3) - ((tid >> 3) & 3)) & 3)) * 8;   // swizzled source chunk
  const int mm = m0 + rA;
  const int s1 = mm & 511;
  const bool fixBlk = (dil > 0) && ((m0 & 511) == 0);  // dil<=64<128: only first block per seq
  const int lr = lane & 15;
  const int quad = lane >> 4;
  const int sw = ((quad + ((lr >> 1) & 3)) & 3) * 8;   // swizzled frag column

  f32x4 acc[4][4];
  #pragma unroll
  for (int i = 0; i < 4; ++i)
    #pragma unroll
    for (int j = 0; j < 4; ++j) {
      acc[i][j][0] = 0.f; acc[i][j][1] = 0.f; acc[i][j][2] = 0.f; acc[i][j][3] = 0.f;
    }

  const int nkt = Ktot >> 6;          // 4 (K=256) or 8 (K=512)
  for (int kt = 0; kt < nkt; ++kt) {
    const bool tap0 = (dil > 0) && (kt < 4);
    const int kkA = (dil > 0) ? ((kt & 3) * 64) : (kt * 64);
    int r = mm;
    if (tap0) r = (s1 >= dil) ? (mm - dil) : mm;       // clamped rows zeroed below
    gload16(A + (long)r * 256 + kkA + cSw,      &lA[tid * 8]);
    gload16(A + (long)r * 256 + kkA + 32 + cSw, &lA[4096 + tid * 8]);
    const u16* bSrc = WT + kt * 64 + cSw;
    gload16(bSrc + (long)rA * Ktot,              &lB[tid * 8]);
    gload16(bSrc + (long)(rA + 128) * Ktot,      &lB[tid * 8 + 4096]);
    gload16(bSrc + 32 + (long)rA * Ktot,         &lB[8192 + tid * 8]);
    gload16(bSrc + 32 + (long)(rA + 128) * Ktot, &lB[8192 + tid * 8 + 4096]);
    __syncthreads();

    if (fixBlk && tap0) {               // block-uniform
      if (rA < dil) {
        uint4 zz; zz.x = 0; zz.y = 0; zz.z = 0; zz.w = 0;
        *(uint4*)&lA[rA * 32 + (tid & 3) * 8] = zz;          // sub0 row zeroed
        *(uint4*)&lA[4096 + rA * 32 + (tid & 3) * 8] = zz;   // sub1 row zeroed
      }
      __syncthreads();
    }

    #pragma unroll
    for (int ss = 0; ss < 2; ++ss) {
      short8 af[4], bfr[4];
      #pragma unroll
      for (int mt = 0; mt < 4; ++mt)
        af[mt] = *(const short8*)&lA[ss * 4096 + (mw * 64 + mt * 16 + lr) * 32 + sw];
      #pragma unroll
      for (int nt = 0; nt < 4; ++nt)
        bfr[nt] = *(const short8*)&lB[ss * 8192 + (nw * 64 + nt * 16 + lr) * 32 + sw];
      #pragma unroll
      for (int mt = 0; mt < 4; ++mt)
        #pragma unroll
        for (int nt = 0; nt < 4; ++nt)
          acc[mt][nt] = __builtin_amdgcn_mfma_f32_16x16x32_bf16(af[mt], bfr[nt], acc[mt][nt], 0, 0, 0);
    }
    __syncthreads();
  }

  // ---- epilogue: bias fold + row stats + LN + lrelu ----
  float biasv[4], gv[4], bv[4];
  #pragma unroll
  for (int nt = 0; nt < 4; ++nt) {
    int n = nw * 64 + nt * 16 + lr;
    biasv[nt] = bias[n]; gv[nt] = g[n]; bv[nt] = b[n];
  }
  #pragma unroll
  for (int mt = 0; mt < 4; ++mt)
    #pragma unroll
    for (int r = 0; r < 4; ++r) {
      float s = 0.f, q = 0.f;
      #pragma unroll
      for (int nt = 0; nt < 4; ++nt) {
        float v = acc[mt][nt][r] + biasv[nt];
        acc[mt][nt][r] = v;
        s += v; q += v * v;
      }
      #pragma unroll
      for (int off = 1; off < 16; off <<= 1) {
        s += __shfl_xor(s, off); q += __shfl_xor(q, off);
      }
      if (lr == 0) {
        int row = mw * 64 + mt * 16 + quad * 4 + r;
        pS[row][nw] = s; pQ[row][nw] = q;
      }
    }
  __syncthreads();
  if (tid < 128) {
    float S = pS[tid][0] + pS[tid][1] + pS[tid][2] + pS[tid][3];
    float Q = pQ[tid][0] + pQ[tid][1] + pQ[tid][2] + pQ[tid][3];
    float mu = S * 0.00390625f;
    float var = Q * 0.00390625f - mu * mu;
    muA[tid] = mu; rsA[tid] = rsqrtf(var + 1e-5f);
  }
  __syncthreads();
  #pragma unroll
  for (int mt = 0; mt < 4; ++mt)
    #pragma unroll
    for (int r = 0; r < 4; ++r) {
      int row = mw * 64 + mt * 16 + quad * 4 + r;
      float mu = muA[row], rs = rsA[row];
      #pragma unroll
      for (int nt = 0; nt < 4; ++nt) {
        float y = (acc[mt][nt][r] - mu) * rs * gv[nt] + bv[nt];
        y = y >= 0.f ? y : 0.01f * y;
        Out[(long)(m0 + row) * 256 + nw * 64 + nt * 16 + lr] = f2b(y);
      }
    }
}

// ---------------- fused GEMM3(e,g) + gate + residual + next-layer LN1, BK=64 ----------------
// M=64 x N=256, 256 thr / 4 waves; wave computes both e and g for its 64 cols.

__global__ __launch_bounds__(256, 2) void gemm_gate_ln_k(
    const u16* __restrict__ P, const u16* __restrict__ WTe, const u16* __restrict__ WTg,
    const float* __restrict__ be, const float* __restrict__ bg,
    const float* __restrict__ g, const float* __restrict__ b,
    u16* __restrict__ h, u16* __restrict__ tOut, int doLN)
{
  __shared__ u16 lA[64 * 64];         // sub0 [0,2048), sub1 [2048,4096)
  __shared__ u16 lBe[256 * 64];       // sub0 [0,8192), sub1 [8192,16384)
  __shared__ u16 lBg[256 * 64];
  __shared__ float pS[64][4], pQ[64][4];
  __shared__ float muA[64], rsA[64];
  const int tid = threadIdx.x;
  const int lane = tid & 63;
  const int wv = tid >> 6;
  const int wc = wv * 64;
  const int m0 = blockIdx.x * 64;
  const int rA = tid >> 2;
  const int cSw = ((((tid & 3) - ((tid >> 3) & 3)) & 3)) * 8;
  const int lr = lane & 15;
  const int quad = lane >> 4;
  const int sw = ((quad + ((lr >> 1) & 3)) & 3) * 8;

  f32x4 accE[4][4], accG[4][4];
  #pragma unroll
  for (int i = 0; i < 4; ++i)
    #pragma unroll
    for (int j = 0; j < 4; ++j) {
      accE[i][j][0] = 0.f; accE[i][j][1] = 0.f; accE[i][j][2] = 0.f; accE[i][j][3] = 0.f;
      accG[i][j][0] = 0.f; accG[i][j][1] = 0.f; accG[i][j][2] = 0.f; accG[i][j][3] = 0.f;
    }

  for (int kt = 0; kt < 4; ++kt) {
    const int kk = kt * 64;
    gload16(P + (long)(m0 + rA) * 256 + kk + cSw,      &lA[tid * 8]);
    gload16(P + (long)(m0 + rA) * 256 + kk + 32 + cSw, &lA[2048 + tid * 8]);
    const long bofs = (long)rA * 256 + kk + cSw;
    #pragma unroll
    for (int j = 0; j < 4; ++j) {
      gload16(WTe + bofs + (long)(64 * j) * 256,      &lBe[tid * 8 + j * 2048]);
      gload16(WTg + bofs + (long)(64 * j) * 256,      &lBg[tid * 8 + j * 2048]);
      gload16(WTe + bofs + 32 + (long)(64 * j) * 256, &lBe[8192 + tid * 8 + j * 2048]);
      gload16(WTg + bofs + 32 + (long)(64 * j) * 256, &lBg[8192 + tid * 8 + j * 2048]);
    }
    __syncthreads();

    #pragma unroll
    for (int ss = 0; ss < 2; ++ss) {
      short8 af[4], bfe[4], bfg[4];
      #pragma unroll
      for (int mt = 0; mt < 4; ++mt)
        af[mt] = *(const short8*)&lA[ss * 2048 + (mt * 16 + lr) * 32 + sw];
      #pragma unroll
      for (int nt = 0; nt < 4; ++nt) {
        bfe[nt] = *(const short8*)&lBe[ss * 8192 + (wc + nt * 16 + lr) * 32 + sw];
        bfg[nt] = *(const short8*)&lBg[ss * 8192 + (wc + nt * 16 + lr) * 32 + sw];
      }
      #pragma unroll
      for (int mt = 0; mt < 4; ++mt)
        #pragma unroll
        for (int nt = 0; nt < 4; ++nt) {
          accE[mt][nt] = __builtin_amdgcn_mfma_f32_16x16x32_bf16(af[mt], bfe[nt], accE[mt][nt], 0, 0, 0);
          accG[mt][nt] = __builtin_amdgcn_mfma_f32_16x16x32_bf16(af[mt], bfg[nt], accG[mt][nt], 0, 0, 0);
        }
    }
    __syncthreads();
  }

  // ---- epilogue: gate + residual (h RMW) + stats on hn ----
  float bev[4], bgv[4];
  #pragma unroll
  for (int nt = 0; nt < 4; ++nt) {
    int n = wc + nt * 16 + lr;
    bev[nt] = be[n]; bgv[nt] = bg[n];
  }
  #pragma unroll
  for (int mt = 0; mt < 4; ++mt)
    #pragma unroll
    for (int r = 0; r < 4; ++r) {
      int row = mt * 16 + quad * 4 + r;
      long off = (long)(m0 + row) * 256;
      float s = 0.f, q = 0.f;
      #pragma unroll
      for (int nt = 0; nt < 4; ++nt) {
        int n = wc + nt * 16 + lr;
        float e = accE[mt][nt][r] + bev[nt];
        float gg = accG[mt][nt][r] + bgv[nt];
        float hv = b2f(h[off + n]);
        float hn = e * (1.f / (1.f + expf(-gg))) + hv;
        h[off + n] = f2b(hn);
        accE[mt][nt][r] = hn;
        s += hn; q += hn * hn;
      }
      #pragma unroll
      for (int off2 = 1; off2 < 16; off2 <<= 1) {
        s += __shfl_xor(s, off2); q += __shfl_xor(q, off2);
      }
      if (lr == 0) { pS[row][wv] = s; pQ[row][wv] = q; }
    }
  __syncthreads();
  if (tid < 64) {
    float S = pS[tid][0] + pS[tid][1] + pS[tid][2] + pS[tid][3];
    float Q = pQ[tid][0] + pQ[tid][1] + pQ[tid][2] + pQ[tid][3];
    float mu = S * 0.00390625f;
    float var = Q * 0.00390625f - mu * mu;
    muA[tid] = mu; rsA[tid] = rsqrtf(var + 1e-5f);
  }
  __syncthreads();
  if (doLN) {
    float gv[4], bv[4];
    #pragma unroll
    for (int nt = 0; nt < 4; ++nt) {
      int n = wc + nt * 16 + lr;
      gv[nt] = g[n]; bv[nt] = b[n];
    }
    #pragma unroll
    for (int mt = 0; mt < 4; ++mt)
      #pragma unroll
      for (int r = 0; r < 4; ++r) {
        int row = mt * 16 + quad * 4 + r;
        float mu = muA[row], rs = rsA[row];
        #pragma unroll
        for (int nt = 0; nt < 4; ++nt) {
          float y = (accE[mt][nt][r] - mu) * rs * gv[nt] + bv[nt];
          y = y >= 0.f ? y : 0.01f * y;
          tOut[(long)(m0 + row) * 256 + wc + nt * 16 + lr] = f2b(y);
        }
      }
  }
}

// ---------------- final: MFMA logits [M,32], log_softmax, gather next token ----------------

__global__ __launch_bounds__(256) void final_k(const u16* __restrict__ h, const u16* __restrict__ WTo,
                                               const float* __restrict__ outb, const int* __restrict__ x,
                                               float* __restrict__ out) {
  __shared__ u16 lW[32 * 264];
  const int tid = threadIdx.x;
  const int lane = tid & 63;
  const int wv = tid >> 6;
  const int mBase = blockIdx.x * 256 + wv * 64;

  #pragma unroll
  for (int j = 0; j < 4; ++j) {
    int chunk = tid + 256 * j;
    int v = chunk >> 5, k8 = chunk & 31;
    uint4 w4 = *(const uint4*)(WTo + v * 256 + k8 * 8);
    *(uint4*)&lW[v * 264 + k8 * 8] = w4;
  }
  __syncthreads();

  const int lq = (lane >> 4) * 8;
  const int lr = lane & 15;
  const int quad = lane >> 4;

  f32x4 acc[4][2];
  #pragma unroll
  for (int mt = 0; mt < 4; ++mt) {
    acc[mt][0][0] = 0.f; acc[mt][0][1] = 0.f; acc[mt][0][2] = 0.f; acc[mt][0][3] = 0.f;
    acc[mt][1][0] = 0.f; acc[mt][1][1] = 0.f; acc[mt][1][2] = 0.f; acc[mt][1][3] = 0.f;
  }

  for (int kt = 0; kt < 8; ++kt) {
    short8 bf0 = *(const short8*)&lW[lr * 264 + kt * 32 + lq];
    short8 bf1 = *(const short8*)&lW[(16 + lr) * 264 + kt * 32 + lq];
    #pragma unroll
    for (int mt = 0; mt < 4; ++mt) {
      short8 af = *(const short8*)(h + (long)(mBase + mt * 16 + lr) * 256 + kt * 32 + lq);
      acc[mt][0] = __builtin_amdgcn_mfma_f32_16x16x32_bf16(af, bf0, acc[mt][0], 0, 0, 0);
      acc[mt][1] = __builtin_amdgcn_mfma_f32_16x16x32_bf16(af, bf1, acc[mt][1], 0, 0, 0);
    }
  }

  float ob0 = outb[lr], ob1 = outb[16 + lr];
  #pragma unroll
  for (int mt = 0; mt < 4; ++mt)
    #pragma unroll
    for (int r = 0; r < 4; ++r) {
      int row = mBase + mt * 16 + quad * 4 + r;
      float lo = acc[mt][0][r] + ob0;
      float hi = acc[mt][1][r] + ob1;
      float mx = fmaxf(lo, hi);
      #pragma unroll
      for (int o = 1; o < 16; o <<= 1) mx = fmaxf(mx, __shfl_xor(mx, o));
      float se = expf(lo - mx) + expf(hi - mx);
      #pragma unroll
      for (int o = 1; o < 16; o <<= 1) se += __shfl_xor(se, o);
      int s = row & 511;
      int xa = (s == 511) ? row : (row + 1);
      int tok = x[xa];
      float lg = (tok < 16) ? lo : hi;
      float lp = lg - mx - logf(se);
      if (s != 511 && lr == (tok & 15))
        out[(row >> 9) * 511 + s] = lp;
    }
}

// ---------------- launch ----------------

extern "C" void kernel_launch(void* const* d_in, const int* in_sizes, int n_in,
                              void* d_out, int out_size, void* d_ws, size_t ws_size,
                              hipStream_t stream) {
  const int*   x    = (const int*)d_in[0];
  const float* z    = (const float*)d_in[1];
  const float* emb  = (const float*)d_in[2];
  const float* latW = (const float*)d_in[3];
  const float* latb = (const float*)d_in[4];
  const float* ln1g = (const float*)d_in[5];
  const float* ln1b = (const float*)d_in[6];
  const float* w1   = (const float*)d_in[7];
  const float* b1   = (const float*)d_in[8];
  const float* ln2g = (const float*)d_in[9];
  const float* ln2b = (const float*)d_in[10];
  const float* wd   = (const float*)d_in[11];
  const float* bd   = (const float*)d_in[12];
  const float* ln3g = (const float*)d_in[13];
  const float* ln3b = (const float*)d_in[14];
  const float* we   = (const float*)d_in[15];
  const float* be   = (const float*)d_in[16];
  const float* wg   = (const float*)d_in[17];
  const float* bg   = (const float*)d_in[18];
  const float* outW = (const float*)d_in[19];
  const float* outb = (const float*)d_in[20];

  char* ws = (char*)d_ws;
  u16*   h    = (u16*)(ws + 0);               //  67108864  bf16 residual
  u16*   bufA = (u16*)(ws + 67108864);        //  67108864
  u16*   bufB = (u16*)(ws + 134217728);       //  67108864
  float* zlat = (float*)(ws + 201326592);     //    262144
  u16*   wT1  = (u16*)(ws + 201588736);       //    917504  [i][n][k]
  u16*   wTd  = (u16*)(ws + 202506240);       //   1835008  [i][n][tap*256+k]
  u16*   wTeg = (u16*)(ws + 204341248);       //   1835008  [i][src][n][k]
  u16*   wTo  = (u16*)(ws + 206176256);       //     16384  [v][k]
  // total 206192640 bytes

  conv_w1_k <<<1792, 256, 0, stream>>>(w1, wT1);
  conv_wd_k <<<3584, 256, 0, stream>>>(wd, wTd);
  conv_weg_k<<<3584, 256, 0, stream>>>(we, wg, wTeg);
  conv_wo_k <<<32, 256, 0, stream>>>(outW, wTo);
  zlat_k    <<<256, 256, 0, stream>>>(z, latW, latb, zlat);
  embed_ln_k<<<M_DIM / 4, 256, 0, stream>>>(x, emb, zlat, ln1g, ln1b, h, bufA);

  u16* X = bufA;   // t lives here at loop top
  u16* Y = bufB;
  for (int i = 0; i < NL; ++i) {
    int d = 1 << i;
    int doLN = (i < NL - 1) ? 1 : 0;
    int ni = doLN ? (i + 1) : i;
    // t(X) @ w1 + b1 -> LN2+lrelu -> v(Y)
    gemm_ln_k<<<M_DIM / 128, 512, 0, stream>>>(
        X, wT1 + i * 65536, 256, 0, b1 + i * 256, ln2g + i * 256, ln2b + i * 256, Y);
    // dilated conv on v(Y) -> LN3+lrelu -> p(X)
    gemm_ln_k<<<M_DIM / 128, 512, 0, stream>>>(
        Y, wTd + i * 131072, 512, d, bd + i * 256, ln3g + i * 256, ln3b + i * 256, X);
    // p(X) @ [we,wg] + gate + residual h ; next LN1+lrelu -> t(Y)
    gemm_gate_ln_k<<<M_DIM / 64, 256, 0, stream>>>(
        X, wTeg + i * 131072, wTeg + i * 131072 + 65536, be + i * 256, bg + i * 256,
        ln1g + ni * 256, ln1b + ni * 256, h, Y, doLN);
    u16* tmp = X; X = Y; Y = tmp;
  }

  final_k<<<M_DIM / 256, 256, 0, stream>>>(h, wTo, outb, x, (float*)d_out);
}

// Round 12
// 1474.080 us; speedup vs baseline: 1.0893x; 1.0893x over previous
//
#include <hip/hip_runtime.h>

typedef unsigned short u16;
typedef unsigned int   u32;
typedef __attribute__((ext_vector_type(8))) short short8;
typedef __attribute__((ext_vector_type(4))) float f32x4;

struct __align__(8) u16x4 { u16 x, y, z, w; };

#define NL 7
#define M_DIM 131072              // B*S = 256*512

__device__ __forceinline__ float b2f(u16 u) {
  union { float f; u32 i; } c; c.i = ((u32)u) << 16; return c.f;
}
__device__ __forceinline__ u16 f2b(float f) {
  union { float f; u32 i; } c; c.f = f;
  u32 r = c.i + 0x7FFFu + ((c.i >> 16) & 1u);
  return (u16)(r >> 16);
}
__device__ __forceinline__ void gload16(const void* g, void* l) {
  __builtin_amdgcn_global_load_lds((const __attribute__((address_space(1))) void*)g,
                                   (__attribute__((address_space(3))) void*)l, 16, 0, 0);
}

// ---------------- weight conversion (fp32 -> bf16, transposed to [N][K]) ----------------

__global__ __launch_bounds__(256) void conv_w1_k(const float* __restrict__ w1, u16* __restrict__ wT) {
  int idx = blockIdx.x * 256 + threadIdx.x;            // NL*256*256 ; [i][n][k]
  int i = idx >> 16, rem = idx & 65535;
  int n = rem >> 8, k = rem & 255;
  wT[idx] = f2b(w1[(i << 16) + (k << 8) + n]);
}

__global__ __launch_bounds__(256) void conv_wd_k(const float* __restrict__ wd, u16* __restrict__ wT) {
  int idx = blockIdx.x * 256 + threadIdx.x;            // NL*256*512 ; [i][n][k2], k2=tap*256+k
  int i = idx / 131072, rem = idx & 131071;
  int n = rem >> 9, k2 = rem & 511;
  int tap = k2 >> 8, k = k2 & 255;
  wT[idx] = f2b(wd[(((i * 2 + tap) << 8) + k) * 256 + n]);
}

__global__ __launch_bounds__(256) void conv_weg_k(const float* __restrict__ we, const float* __restrict__ wg,
                                                  u16* __restrict__ wT) {
  int idx = blockIdx.x * 256 + threadIdx.x;            // NL*2*256*256 ; [i][src][n][k]
  int i = idx / 131072, rem = idx & 131071;
  int src = rem >> 16, n = (rem >> 8) & 255, k = rem & 255;
  const float* W = src ? wg : we;
  wT[idx] = f2b(W[((i << 8) + k) * 256 + n]);
}

__global__ __launch_bounds__(256) void conv_wo_k(const float* __restrict__ outW, u16* __restrict__ wTo) {
  int idx = blockIdx.x * 256 + threadIdx.x;            // 32*256 ; [v][k]
  int v = idx >> 8, k = idx & 255;
  wTo[idx] = f2b(outW[k * 32 + v]);
}

// ---------------- zlat = z @ latent_W + latent_b  [256,256] fp32 ----------------

__global__ __launch_bounds__(256) void zlat_k(const float* __restrict__ z, const float* __restrict__ W,
                                              const float* __restrict__ bias, float* __restrict__ zlat) {
  int b = blockIdx.x, c = threadIdx.x;
  float acc = bias[c];
  for (int l = 0; l < 256; ++l) acc += z[b * 256 + l] * W[l * 256 + c];
  zlat[b * 256 + c] = acc;
}

// ---------------- embed: h = bf16(emb[x] + zlat) ----------------

__global__ __launch_bounds__(256) void embed_k(const int* __restrict__ x, const float* __restrict__ emb,
                                               const float* __restrict__ zlat, u16* __restrict__ h) {
  int wave = threadIdx.x >> 6, lane = threadIdx.x & 63;
  int r = blockIdx.x * 4 + wave;
  int c = lane * 4;
  int tok = x[r];
  int bi = r >> 9;
  float4 ev = *(const float4*)&emb[tok * 256 + c];
  float4 zv = *(const float4*)&zlat[bi * 256 + c];
  u16x4 hb;
  hb.x = f2b(ev.x + zv.x); hb.y = f2b(ev.y + zv.y);
  hb.z = f2b(ev.z + zv.z); hb.w = f2b(ev.w + zv.w);
  *(u16x4*)&h[(long)r * 256 + c] = hb;
}

// ---------------- gemm1v2: V = lrelu(LN2( lrelu(LN1(h)) @ w1 + b1 )) ----------------
// M=64 x N=256, 256 thr / 4 waves. Prologue: stage h-tile -> LN1+lrelu -> lA[64x264]
// (264-stride = 2-way banks, free). K-loop stages only B per kt (r6 swizzle, 16 KB).
// LN2 stats epilogue as r6. No t buffer anywhere.

__global__ __launch_bounds__(256, 2) void gemm1_k(
    const u16* __restrict__ h, const u16* __restrict__ WT,
    const float* __restrict__ ln1g, const float* __restrict__ ln1b,
    const float* __restrict__ bias,
    const float* __restrict__ ln2g, const float* __restrict__ ln2b,
    u16* __restrict__ V)
{
  __shared__ __align__(16) u16 lA[64 * 264];     // 33792 B, LN1(h) tile
  __shared__ __align__(16) u16 lB[256 * 32];     // 16384 B, per-kt B staging
  __shared__ float pS[64][4], pQ[64][4];
  __shared__ float muA[64], rsA[64];
  const int tid = threadIdx.x;
  const int lane = tid & 63;
  const int wv = tid >> 6;            // 0..3
  const int wc = wv * 64;
  const int m0 = blockIdx.x * 64;
  const int rA = tid >> 2;            // 0..63 (B staging row base)
  const int cSw = ((((tid & 3) - ((tid >> 3) & 3)) & 3)) * 8;   // swizzled source chunk
  const int lr = lane & 15;
  const int quad = lane >> 4;
  const int lq = quad * 8;
  const int sw = ((quad + ((lr >> 1) & 3)) & 3) * 8;            // swizzled frag col (lB only)

  // ---- prologue: LN1 + lrelu of 16 rows per wave -> lA ----
  {
    const int half = lane >> 5, l5 = lane & 31;
    float4 ga = *(const float4*)&ln1g[l5 * 8];
    float4 gb = *(const float4*)&ln1g[l5 * 8 + 4];
    float4 ba = *(const float4*)&ln1b[l5 * 8];
    float4 bb = *(const float4*)&ln1b[l5 * 8 + 4];
    #pragma unroll 4
    for (int it = 0; it < 8; ++it) {
      int row = wv * 16 + it * 2 + half;
      uint4 hv = *(const uint4*)(h + (long)(m0 + row) * 256 + l5 * 8);
      float v0 = b2f((u16)(hv.x & 0xffff)), v1 = b2f((u16)(hv.x >> 16));
      float v2 = b2f((u16)(hv.y & 0xffff)), v3 = b2f((u16)(hv.y >> 16));
      float v4 = b2f((u16)(hv.z & 0xffff)), v5 = b2f((u16)(hv.z >> 16));
      float v6 = b2f((u16)(hv.w & 0xffff)), v7 = b2f((u16)(hv.w >> 16));
      float s = v0 + v1 + v2 + v3 + v4 + v5 + v6 + v7;
      float q = v0*v0 + v1*v1 + v2*v2 + v3*v3 + v4*v4 + v5*v5 + v6*v6 + v7*v7;
      #pragma unroll
      for (int o = 1; o < 32; o <<= 1) { s += __shfl_xor(s, o); q += __shfl_xor(q, o); }
      float mu = s * 0.00390625f;
      float var = q * 0.00390625f - mu * mu;
      float rs = rsqrtf(var + 1e-5f);
      float y0 = (v0 - mu) * rs * ga.x + ba.x; y0 = y0 >= 0.f ? y0 : 0.01f * y0;
      float y1 = (v1 - mu) * rs * ga.y + ba.y; y1 = y1 >= 0.f ? y1 : 0.01f * y1;
      float y2 = (v2 - mu) * rs * ga.z + ba.z; y2 = y2 >= 0.f ? y2 : 0.01f * y2;
      float y3 = (v3 - mu) * rs * ga.w + ba.w; y3 = y3 >= 0.f ? y3 : 0.01f * y3;
      float y4 = (v4 - mu) * rs * gb.x + bb.x; y4 = y4 >= 0.f ? y4 : 0.01f * y4;
      float y5 = (v5 - mu) * rs * gb.y + bb.y; y5 = y5 >= 0.f ? y5 : 0.01f * y5;
      float y6 = (v6 - mu) * rs * gb.z + bb.z; y6 = y6 >= 0.f ? y6 : 0.01f * y6;
      float y7 = (v7 - mu) * rs * gb.w + bb.w; y7 = y7 >= 0.f ? y7 : 0.01f * y7;
      uint4 ov;
      ov.x = (u32)f2b(y0) | ((u32)f2b(y1) << 16);
      ov.y = (u32)f2b(y2) | ((u32)f2b(y3) << 16);
      ov.z = (u32)f2b(y4) | ((u32)f2b(y5) << 16);
      ov.w = (u32)f2b(y6) | ((u32)f2b(y7) << 16);
      *(uint4*)&lA[row * 264 + l5 * 8] = ov;
    }
  }

  f32x4 acc[4][4];
  #pragma unroll
  for (int i = 0; i < 4; ++i)
    #pragma unroll
    for (int j = 0; j < 4; ++j) {
      acc[i][j][0] = 0.f; acc[i][j][1] = 0.f; acc[i][j][2] = 0.f; acc[i][j][3] = 0.f;
    }

  for (int kt = 0; kt < 8; ++kt) {
    const int kk = kt * 32;
    const long bofs = (long)rA * 256 + kk + cSw;
    #pragma unroll
    for (int j = 0; j < 4; ++j)
      gload16(WT + bofs + (long)(64 * j) * 256, &lB[tid * 8 + j * 2048]);
    __syncthreads();                   // lA ready (kt=0) / prev lB reads done; lB staged

    short8 af[4], bfr[4];
    #pragma unroll
    for (int mt = 0; mt < 4; ++mt)
      af[mt] = *(const short8*)&lA[(mt * 16 + lr) * 264 + kk + lq];
    #pragma unroll
    for (int nt = 0; nt < 4; ++nt)
      bfr[nt] = *(const short8*)&lB[(wc + nt * 16 + lr) * 32 + sw];
    #pragma unroll
    for (int mt = 0; mt < 4; ++mt)
      #pragma unroll
      for (int nt = 0; nt < 4; ++nt)
        acc[mt][nt] = __builtin_amdgcn_mfma_f32_16x16x32_bf16(af[mt], bfr[nt], acc[mt][nt], 0, 0, 0);
    __syncthreads();
  }

  // ---- epilogue: bias + LN2 + lrelu -> V ----
  float biasv[4], gv[4], bv[4];
  #pragma unroll
  for (int nt = 0; nt < 4; ++nt) {
    int n = wc + nt * 16 + lr;
    biasv[nt] = bias[n]; gv[nt] = ln2g[n]; bv[nt] = ln2b[n];
  }
  #pragma unroll
  for (int mt = 0; mt < 4; ++mt)
    #pragma unroll
    for (int r = 0; r < 4; ++r) {
      float s = 0.f, q = 0.f;
      #pragma unroll
      for (int nt = 0; nt < 4; ++nt) {
        float v = acc[mt][nt][r] + biasv[nt];
        acc[mt][nt][r] = v;
        s += v; q += v * v;
      }
      #pragma unroll
      for (int o = 1; o < 16; o <<= 1) { s += __shfl_xor(s, o); q += __shfl_xor(q, o); }
      if (lr == 0) { pS[mt * 16 + quad * 4 + r][wv] = s; pQ[mt * 16 + quad * 4 + r][wv] = q; }
    }
  __syncthreads();
  if (tid < 64) {
    float S = pS[tid][0] + pS[tid][1] + pS[tid][2] + pS[tid][3];
    float Q = pQ[tid][0] + pQ[tid][1] + pQ[tid][2] + pQ[tid][3];
    float mu = S * 0.00390625f;
    float var = Q * 0.00390625f - mu * mu;
    muA[tid] = mu; rsA[tid] = rsqrtf(var + 1e-5f);
  }
  __syncthreads();
  #pragma unroll
  for (int mt = 0; mt < 4; ++mt)
    #pragma unroll
    for (int r = 0; r < 4; ++r) {
      int row = mt * 16 + quad * 4 + r;
      float mu = muA[row], rs = rsA[row];
      #pragma unroll
      for (int nt = 0; nt < 4; ++nt) {
        float y = (acc[mt][nt][r] - mu) * rs * gv[nt] + bv[nt];
        y = y >= 0.f ? y : 0.01f * y;
        V[(long)(m0 + row) * 256 + wc + nt * 16 + lr] = f2b(y);
      }
    }
}

// ---------------- dil GEMM + bias + LN3 + lrelu (r10 BK=32, M=128) ----------------

__global__ __launch_bounds__(512, 4) void gemm_ln_k(
    const u16* __restrict__ A, const u16* __restrict__ WT, int Ktot, int dil,
    const float* __restrict__ bias, const float* __restrict__ g, const float* __restrict__ b,
    u16* __restrict__ Out)
{
  __shared__ u16 lA[128 * 32];
  __shared__ u16 lB[256 * 32];
  __shared__ float pS[128][4], pQ[128][4];
  __shared__ float muA[128], rsA[128];
  const int tid = threadIdx.x;
  const int lane = tid & 63;
  const int wv = tid >> 6;            // 0..7
  const int mw = wv >> 2;             // 0..1
  const int nw = wv & 3;              // 0..3
  const int m0 = blockIdx.x * 128;
  const int rA = tid >> 2;            // 0..127
  const int cSw = ((((tid & 3) - ((tid >> 3) & 3)) & 3)) * 8;
  const int mm = m0 + rA;
  const int s1 = mm & 511;
  const bool fixBlk = (dil > 0) && ((m0 & 511) == 0);
  const int lr = lane & 15;
  const int quad = lane >> 4;
  const int sw = ((quad + ((lr >> 1) & 3)) & 3) * 8;

  f32x4 acc[4][4];
  #pragma unroll
  for (int i = 0; i < 4; ++i)
    #pragma unroll
    for (int j = 0; j < 4; ++j) {
      acc[i][j][0] = 0.f; acc[i][j][1] = 0.f; acc[i][j][2] = 0.f; acc[i][j][3] = 0.f;
    }

  const int nkt = Ktot >> 5;
  for (int kt = 0; kt < nkt; ++kt) {
    const int kk = (kt & 7) * 32;
    int r = mm;
    if (dil > 0 && kt < 8) r = (s1 >= dil) ? (mm - dil) : mm;
    gload16(A + (long)r * 256 + kk + cSw, &lA[tid * 8]);
    const u16* bSrc = WT + kt * 32 + cSw;
    gload16(bSrc + (long)rA * Ktot,         &lB[tid * 8]);
    gload16(bSrc + (long)(rA + 128) * Ktot, &lB[tid * 8 + 4096]);
    __syncthreads();

    if (fixBlk && kt < 8) {
      if (rA < dil) {
        uint4 zz; zz.x = 0; zz.y = 0; zz.z = 0; zz.w = 0;
        *(uint4*)&lA[rA * 32 + (tid & 3) * 8] = zz;
      }
      __syncthreads();
    }

    short8 af[4], bfr[4];
    #pragma unroll
    for (int mt = 0; mt < 4; ++mt)
      af[mt] = *(const short8*)&lA[(mw * 64 + mt * 16 + lr) * 32 + sw];
    #pragma unroll
    for (int nt = 0; nt < 4; ++nt)
      bfr[nt] = *(const short8*)&lB[(nw * 64 + nt * 16 + lr) * 32 + sw];
    #pragma unroll
    for (int mt = 0; mt < 4; ++mt)
      #pragma unroll
      for (int nt = 0; nt < 4; ++nt)
        acc[mt][nt] = __builtin_amdgcn_mfma_f32_16x16x32_bf16(af[mt], bfr[nt], acc[mt][nt], 0, 0, 0);
    __syncthreads();
  }

  float biasv[4], gv[4], bv[4];
  #pragma unroll
  for (int nt = 0; nt < 4; ++nt) {
    int n = nw * 64 + nt * 16 + lr;
    biasv[nt] = bias[n]; gv[nt] = g[n]; bv[nt] = b[n];
  }
  #pragma unroll
  for (int mt = 0; mt < 4; ++mt)
    #pragma unroll
    for (int r = 0; r < 4; ++r) {
      float s = 0.f, q = 0.f;
      #pragma unroll
      for (int nt = 0; nt < 4; ++nt) {
        float v = acc[mt][nt][r] + biasv[nt];
        acc[mt][nt][r] = v;
        s += v; q += v * v;
      }
      #pragma unroll
      for (int off = 1; off < 16; off <<= 1) {
        s += __shfl_xor(s, off); q += __shfl_xor(q, off);
      }
      if (lr == 0) {
        int row = mw * 64 + mt * 16 + quad * 4 + r;
        pS[row][nw] = s; pQ[row][nw] = q;
      }
    }
  __syncthreads();
  if (tid < 128) {
    float S = pS[tid][0] + pS[tid][1] + pS[tid][2] + pS[tid][3];
    float Q = pQ[tid][0] + pQ[tid][1] + pQ[tid][2] + pQ[tid][3];
    float mu = S * 0.00390625f;
    float var = Q * 0.00390625f - mu * mu;
    muA[tid] = mu; rsA[tid] = rsqrtf(var + 1e-5f);
  }
  __syncthreads();
  #pragma unroll
  for (int mt = 0; mt < 4; ++mt)
    #pragma unroll
    for (int r = 0; r < 4; ++r) {
      int row = mw * 64 + mt * 16 + quad * 4 + r;
      float mu = muA[row], rs = rsA[row];
      #pragma unroll
      for (int nt = 0; nt < 4; ++nt) {
        float y = (acc[mt][nt][r] - mu) * rs * gv[nt] + bv[nt];
        y = y >= 0.f ? y : 0.01f * y;
        Out[(long)(m0 + row) * 256 + nw * 64 + nt * 16 + lr] = f2b(y);
      }
    }
}

// ---------------- gate: h = (P@we+be)*sigmoid(P@wg+bg) + h  (r9-measured, no LN/tOut) ----------------

__global__ __launch_bounds__(256, 2) void gate_k(
    const u16* __restrict__ P, const u16* __restrict__ WTe, const u16* __restrict__ WTg,
    const float* __restrict__ be, const float* __restrict__ bg, u16* __restrict__ h)
{
  __shared__ u16 lA[64 * 32];
  __shared__ u16 lBe[256 * 32];
  __shared__ u16 lBg[256 * 32];
  const int tid = threadIdx.x;
  const int lane = tid & 63;
  const int wv = tid >> 6;
  const int wc = wv * 64;
  const int m0 = blockIdx.x * 64;
  const int rA = tid >> 2;
  const int cSw = ((((tid & 3) - ((tid >> 3) & 3)) & 3)) * 8;
  const int lr = lane & 15;
  const int quad = lane >> 4;
  const int sw = ((quad + ((lr >> 1) & 3)) & 3) * 8;

  f32x4 accE[4][4], accG[4][4];
  #pragma unroll
  for (int i = 0; i < 4; ++i)
    #pragma unroll
    for (int j = 0; j < 4; ++j) {
      accE[i][j][0] = 0.f; accE[i][j][1] = 0.f; accE[i][j][2] = 0.f; accE[i][j][3] = 0.f;
      accG[i][j][0] = 0.f; accG[i][j][1] = 0.f; accG[i][j][2] = 0.f; accG[i][j][3] = 0.f;
    }

  for (int kt = 0; kt < 8; ++kt) {
    const int kk = kt * 32;
    gload16(P + (long)(m0 + rA) * 256 + kk + cSw, &lA[tid * 8]);
    const long bofs = (long)rA * 256 + kk + cSw;
    #pragma unroll
    for (int j = 0; j < 4; ++j) {
      gload16(WTe + bofs + (long)(64 * j) * 256, &lBe[tid * 8 + j * 2048]);
      gload16(WTg + bofs + (long)(64 * j) * 256, &lBg[tid * 8 + j * 2048]);
    }
    __syncthreads();

    short8 af[4], bfe[4], bfg[4];
    #pragma unroll
    for (int mt = 0; mt < 4; ++mt)
      af[mt] = *(const short8*)&lA[(mt * 16 + lr) * 32 + sw];
    #pragma unroll
    for (int nt = 0; nt < 4; ++nt) {
      bfe[nt] = *(const short8*)&lBe[(wc + nt * 16 + lr) * 32 + sw];
      bfg[nt] = *(const short8*)&lBg[(wc + nt * 16 + lr) * 32 + sw];
    }
    #pragma unroll
    for (int mt = 0; mt < 4; ++mt)
      #pragma unroll
      for (int nt = 0; nt < 4; ++nt) {
        accE[mt][nt] = __builtin_amdgcn_mfma_f32_16x16x32_bf16(af[mt], bfe[nt], accE[mt][nt], 0, 0, 0);
        accG[mt][nt] = __builtin_amdgcn_mfma_f32_16x16x32_bf16(af[mt], bfg[nt], accG[mt][nt], 0, 0, 0);
      }
    __syncthreads();
  }

  float bev[4], bgv[4];
  #pragma unroll
  for (int nt = 0; nt < 4; ++nt) {
    int n = wc + nt * 16 + lr;
    bev[nt] = be[n]; bgv[nt] = bg[n];
  }
  #pragma unroll
  for (int mt = 0; mt < 4; ++mt)
    #pragma unroll
    for (int r = 0; r < 4; ++r) {
      int row = mt * 16 + quad * 4 + r;
      long off = (long)(m0 + row) * 256;
      #pragma unroll
      for (int nt = 0; nt < 4; ++nt) {
        int n = wc + nt * 16 + lr;
        float e = accE[mt][nt][r] + bev[nt];
        float gg = accG[mt][nt][r] + bgv[nt];
        float hn = e * (1.f / (1.f + expf(-gg))) + b2f(h[off + n]);
        h[off + n] = f2b(hn);
      }
    }
}

// ---------------- final: MFMA logits [M,32], log_softmax, gather next token ----------------

__global__ __launch_bounds__(256) void final_k(const u16* __restrict__ h, const u16* __restrict__ WTo,
                                               const float* __restrict__ outb, const int* __restrict__ x,
                                               float* __restrict__ out) {
  __shared__ u16 lW[32 * 264];
  const int tid = threadIdx.x;
  const int lane = tid & 63;
  const int wv = tid >> 6;
  const int mBase = blockIdx.x * 256 + wv * 64;

  #pragma unroll
  for (int j = 0; j < 4; ++j) {
    int chunk = tid + 256 * j;
    int v = chunk >> 5, k8 = chunk & 31;
    uint4 w4 = *(const uint4*)(WTo + v * 256 + k8 * 8);
    *(uint4*)&lW[v * 264 + k8 * 8] = w4;
  }
  __syncthreads();

  const int lq = (lane >> 4) * 8;
  const int lr = lane & 15;
  const int quad = lane >> 4;

  f32x4 acc[4][2];
  #pragma unroll
  for (int mt = 0; mt < 4; ++mt) {
    acc[mt][0][0] = 0.f; acc[mt][0][1] = 0.f; acc[mt][0][2] = 0.f; acc[mt][0][3] = 0.f;
    acc[mt][1][0] = 0.f; acc[mt][1][1] = 0.f; acc[mt][1][2] = 0.f; acc[mt][1][3] = 0.f;
  }

  for (int kt = 0; kt < 8; ++kt) {
    short8 bf0 = *(const short8*)&lW[lr * 264 + kt * 32 + lq];
    short8 bf1 = *(const short8*)&lW[(16 + lr) * 264 + kt * 32 + lq];
    #pragma unroll
    for (int mt = 0; mt < 4; ++mt) {
      short8 af = *(const short8*)(h + (long)(mBase + mt * 16 + lr) * 256 + kt * 32 + lq);
      acc[mt][0] = __builtin_amdgcn_mfma_f32_16x16x32_bf16(af, bf0, acc[mt][0], 0, 0, 0);
      acc[mt][1] = __builtin_amdgcn_mfma_f32_16x16x32_bf16(af, bf1, acc[mt][1], 0, 0, 0);
    }
  }

  float ob0 = outb[lr], ob1 = outb[16 + lr];
  #pragma unroll
  for (int mt = 0; mt < 4; ++mt)
    #pragma unroll
    for (int r = 0; r < 4; ++r) {
      int row = mBase + mt * 16 + quad * 4 + r;
      float lo = acc[mt][0][r] + ob0;
      float hi = acc[mt][1][r] + ob1;
      float mx = fmaxf(lo, hi);
      #pragma unroll
      for (int o = 1; o < 16; o <<= 1) mx = fmaxf(mx, __shfl_xor(mx, o));
      float se = expf(lo - mx) + expf(hi - mx);
      #pragma unroll
      for (int o = 1; o < 16; o <<= 1) se += __shfl_xor(se, o);
      int s = row & 511;
      int xa = (s == 511) ? row : (row + 1);
      int tok = x[xa];
      float lg = (tok < 16) ? lo : hi;
      float lp = lg - mx - logf(se);
      if (s != 511 && lr == (tok & 15))
        out[(row >> 9) * 511 + s] = lp;
    }
}

// ---------------- launch ----------------

extern "C" void kernel_launch(void* const* d_in, const int* in_sizes, int n_in,
                              void* d_out, int out_size, void* d_ws, size_t ws_size,
                              hipStream_t stream) {
  const int*   x    = (const int*)d_in[0];
  const float* z    = (const float*)d_in[1];
  const float* emb  = (const float*)d_in[2];
  const float* latW = (const float*)d_in[3];
  const float* latb = (const float*)d_in[4];
  const float* ln1g = (const float*)d_in[5];
  const float* ln1b = (const float*)d_in[6];
  const float* w1   = (const float*)d_in[7];
  const float* b1   = (const float*)d_in[8];
  const float* ln2g = (const float*)d_in[9];
  const float* ln2b = (const float*)d_in[10];
  const float* wd   = (const float*)d_in[11];
  const float* bd   = (const float*)d_in[12];
  const float* ln3g = (const float*)d_in[13];
  const float* ln3b = (const float*)d_in[14];
  const float* we   = (const float*)d_in[15];
  const float* be   = (const float*)d_in[16];
  const float* wg   = (const float*)d_in[17];
  const float* bg   = (const float*)d_in[18];
  const float* outW = (const float*)d_in[19];
  const float* outb = (const float*)d_in[20];

  char* ws = (char*)d_ws;
  u16*   h    = (u16*)(ws + 0);               //  67108864  bf16 residual
  u16*   bufA = (u16*)(ws + 67108864);        //  67108864  v
  u16*   bufB = (u16*)(ws + 134217728);       //  67108864  p
  float* zlat = (float*)(ws + 201326592);     //    262144
  u16*   wT1  = (u16*)(ws + 201588736);       //    917504  [i][n][k]
  u16*   wTd  = (u16*)(ws + 202506240);       //   1835008  [i][n][tap*256+k]
  u16*   wTeg = (u16*)(ws + 204341248);       //   1835008  [i][src][n][k]
  u16*   wTo  = (u16*)(ws + 206176256);       //     16384  [v][k]
  // total 206192640 bytes

  conv_w1_k <<<1792, 256, 0, stream>>>(w1, wT1);
  conv_wd_k <<<3584, 256, 0, stream>>>(wd, wTd);
  conv_weg_k<<<3584, 256, 0, stream>>>(we, wg, wTeg);
  conv_wo_k <<<32, 256, 0, stream>>>(outW, wTo);
  zlat_k    <<<256, 256, 0, stream>>>(z, latW, latb, zlat);
  embed_k   <<<M_DIM / 4, 256, 0, stream>>>(x, emb, zlat, h);

  for (int i = 0; i < NL; ++i) {
    int d = 1 << i;
    // v = lrelu(LN2( lrelu(LN1(h)) @ w1 + b1 ))   -> bufA   (LN1 computed in-kernel from h)
    gemm1_k<<<M_DIM / 64, 256, 0, stream>>>(
        h, wT1 + i * 65536, ln1g + i * 256, ln1b + i * 256, b1 + i * 256,
        ln2g + i * 256, ln2b + i * 256, bufA);
    // p = lrelu(LN3( shift(v,d)@wd0 + v@wd1 + bd )) -> bufB
    gemm_ln_k<<<M_DIM / 128, 512, 0, stream>>>(
        bufA, wTd + i * 131072, 512, d, bd + i * 256, ln3g + i * 256, ln3b + i * 256, bufB);
    // h += (p@we+be) * sigmoid(p@wg+bg)
    gate_k<<<M_DIM / 64, 256, 0, stream>>>(
        bufB, wTeg + i * 131072, wTeg + i * 131072 + 65536, be + i * 256, bg + i * 256, h);
  }

  final_k<<<M_DIM / 256, 256, 0, stream>>>(h, wTo, outb, x, (float*)d_out);
}